// Round 2
// baseline (258.610 us; speedup 1.0000x reference)
//
#include <hip/hip_runtime.h>
#include <stdint.h>

// ---------------------------------------------------------------------------
// IEViT adaptive patch embedding, MI355X/gfx950.
// Static structure (matches reference's deterministic _build_token_index):
//   even patch i=2p  -> subdivided: 4 tokens (16x16 tiles, averaged kernel)
//   odd  patch i=2p+1-> kept:       1 token  (32x32 tile, full kernel)
//   tokens per pair p: [sub(0,0),sub(0,1),sub(1,0),sub(1,1),full] at 5p..5p+4
// Shapes: B=32 C=3 H=512 E=768 G=16 -> out (32, 640, 768) f32
// GEMM-full: M=4096  K=3072 N=768   GEMM-sub: M=16384 K=768 N=768
//
// w_sub derivation (reshape(E,C,2,2,16,16).mean(axis=(2,3)) — NOT quadrant
// averaging): w_sub[e,c,s,t] = 1/4 * sum_{d2,d3} pw[e,c,16*d2+8*d3+(s>>1),
// 16*(s&1)+t]  (rows {s>>1, 8+, 16+, 24+} of column 16*(s&1)+t).
// ---------------------------------------------------------------------------

typedef __attribute__((ext_vector_type(8))) short bf16x8;
typedef __attribute__((ext_vector_type(4))) float f32x4;

__device__ __forceinline__ unsigned short f2bf(float f) {
  union { float f; unsigned u; } v; v.f = f;
  return (unsigned short)((v.u + 0x7fffu + ((v.u >> 16) & 1u)) >> 16);  // RNE
}

// ---- cast patch_weight (768*3*32*32 f32) -> bf16, contiguous (B^T for GEMM-full)
__global__ __launch_bounds__(256) void prep_wfull(const float* __restrict__ pw,
                                                  unsigned short* __restrict__ Wf) {
  int g = blockIdx.x * 256 + threadIdx.x;  // 589,824 float4 groups
  float4 v = ((const float4*)pw)[g];
  ((ushort4*)Wf)[g] = make_ushort4(f2bf(v.x), f2bf(v.y), f2bf(v.z), f2bf(v.w));
}

// ---- averaged 16x16 kernel per the strided-view mean (see header comment)
__global__ __launch_bounds__(256) void prep_wsub(const float* __restrict__ pw,
                                                 unsigned short* __restrict__ Ws) {
  int g = blockIdx.x * 256 + threadIdx.x;  // 147,456 = 768*768/4 float4 groups
  int e = g / 192;
  int rem = g - e * 192;
  int cc = rem >> 6, r2 = rem & 63, s = r2 >> 2, t4 = r2 & 3;
  const float* base = pw + ((size_t)((e * 3 + cc) * 32 + (s >> 1)) * 32
                            + 16 * (s & 1) + 4 * t4);
  float4 q0 = *(const float4*)(base);            // row (s>>1)
  float4 q1 = *(const float4*)(base + 8 * 32);   // row 8+(s>>1)
  float4 q2 = *(const float4*)(base + 16 * 32);  // row 16+(s>>1)
  float4 q3 = *(const float4*)(base + 24 * 32);  // row 24+(s>>1)
  ((ushort4*)Ws)[g] = make_ushort4(
      f2bf(0.25f * (q0.x + q1.x + q2.x + q3.x)),
      f2bf(0.25f * (q0.y + q1.y + q2.y + q3.y)),
      f2bf(0.25f * (q0.z + q1.z + q2.z + q3.z)),
      f2bf(0.25f * (q0.w + q1.w + q2.w + q3.w)));
}

// ---- gather odd patches of x into A_full (4096 x 3072 bf16, row-major)
__global__ __launch_bounds__(256) void gather_full(const float* __restrict__ x,
                                                   unsigned short* __restrict__ Af) {
  int g = blockIdx.x * 256 + threadIdx.x;  // 3,145,728 = 4096*768
  int m = g / 768;                         // A row
  int q = g - m * 768;                     // float4 index within row (k = 4q)
  int b = m >> 7, p = m & 127;
  int i = 2 * p + 1;                       // odd patch
  int r = i >> 4, cpat = i & 15;
  int cc = q >> 8, rem = q & 255, ii = rem >> 3, jj4 = rem & 7;
  const float4* src = (const float4*)(x + ((size_t)((b * 3 + cc) * 512 + (r * 32 + ii)) * 512
                                           + cpat * 32 + jj4 * 4));
  float4 v = *src;
  ((ushort4*)Af)[g] = make_ushort4(f2bf(v.x), f2bf(v.y), f2bf(v.z), f2bf(v.w));
}

// ---- gather the 4 sub-tiles of even patches into A_sub (16384 x 768 bf16)
__global__ __launch_bounds__(256) void gather_sub(const float* __restrict__ x,
                                                  unsigned short* __restrict__ Asub) {
  int g = blockIdx.x * 256 + threadIdx.x;  // 3,145,728 = 16384*192
  int m = g / 192;                         // A row
  int q = g - m * 192;
  int b = m >> 9, t = m & 511;
  int p = t >> 2, s = t & 3, dr = s >> 1, dc = s & 1;
  int i = 2 * p;                           // even patch
  int r = i >> 4, cpat = i & 15;
  int cc = q >> 6, rem = q & 63, ii = rem >> 2, jj4 = rem & 3;
  int srow = r * 32 + dr * 16 + ii;
  int scol = cpat * 32 + dc * 16 + jj4 * 4;
  const float4* src = (const float4*)(x + ((size_t)((b * 3 + cc) * 512 + srow) * 512 + scol));
  float4 v = *src;
  ((ushort4*)Asub)[g] = make_ushort4(f2bf(v.x), f2bf(v.y), f2bf(v.z), f2bf(v.w));
}

// ---- fused 128x128-tile bf16 MFMA GEMM (m97 structure) with scattered epilogue
__global__ __launch_bounds__(256) void gemm_kernel(
    const unsigned short* __restrict__ Af, const unsigned short* __restrict__ Asub,
    const unsigned short* __restrict__ Wf, const unsigned short* __restrict__ Ws,
    const float* __restrict__ bias, float* __restrict__ out) {
  __shared__ unsigned short Asm[128 * 64];
  __shared__ unsigned short Bsm[128 * 64];

  int bid = blockIdx.x;
  const unsigned short* Aptr;
  const unsigned short* Bptr;
  int K, bm, bn, which;
  if (bid < 192) {                 // GEMM-full: 32 x 6 tiles
    which = 0; bm = bid / 6; bn = bid - (bid / 6) * 6;
    Aptr = Af + (size_t)bm * 128 * 3072; Bptr = Wf; K = 3072;
  } else {                         // GEMM-sub: 128 x 6 tiles
    int id = bid - 192;
    which = 1; bm = id / 6; bn = id - (id / 6) * 6;
    Aptr = Asub + (size_t)bm * 128 * 768; Bptr = Ws; K = 768;
  }
  const unsigned short* Brow = Bptr + (size_t)bn * 128 * K;

  int t = threadIdx.x;
  int lane = t & 63;
  int wv = t >> 6, wr = wv >> 1, wc = wv & 1;   // 2x2 waves, 64x64 each
  int lr = lane & 15, lk = lane >> 4;

  f32x4 acc[4][4];
#pragma unroll
  for (int mm = 0; mm < 4; ++mm)
#pragma unroll
    for (int nn = 0; nn < 4; ++nn) acc[mm][nn] = (f32x4){0.f, 0.f, 0.f, 0.f};

  // staging: thread t -> row t/8, 16B chunk (t&7); 4 issues cover 128 rows
  const unsigned short* a_src = Aptr + (size_t)(t >> 3) * K + (t & 7) * 8;
  const unsigned short* b_src = Brow + (size_t)(t >> 3) * K + (t & 7) * 8;
  unsigned short* as_dst = &Asm[t * 8];
  unsigned short* bs_dst = &Bsm[t * 8];

  for (int k0 = 0; k0 < K; k0 += 64) {
#pragma unroll
    for (int is = 0; is < 4; ++is) {
      __builtin_amdgcn_global_load_lds(
          (const __attribute__((address_space(1))) void*)(a_src + (size_t)is * 32 * K + k0),
          (__attribute__((address_space(3))) void*)(as_dst + is * 2048), 16, 0, 0);
      __builtin_amdgcn_global_load_lds(
          (const __attribute__((address_space(1))) void*)(b_src + (size_t)is * 32 * K + k0),
          (__attribute__((address_space(3))) void*)(bs_dst + is * 2048), 16, 0, 0);
    }
    __syncthreads();
#pragma unroll
    for (int kk = 0; kk < 64; kk += 32) {
      bf16x8 af[4], bf[4];
#pragma unroll
      for (int mm = 0; mm < 4; ++mm)
        af[mm] = *(const bf16x8*)&Asm[(wr * 64 + mm * 16 + lr) * 64 + kk + lk * 8];
#pragma unroll
      for (int nn = 0; nn < 4; ++nn)
        bf[nn] = *(const bf16x8*)&Bsm[(wc * 64 + nn * 16 + lr) * 64 + kk + lk * 8];
#pragma unroll
      for (int mm = 0; mm < 4; ++mm)
#pragma unroll
        for (int nn = 0; nn < 4; ++nn)
          acc[mm][nn] = __builtin_amdgcn_mfma_f32_16x16x32_bf16(af[mm], bf[nn], acc[mm][nn], 0, 0, 0);
    }
    __syncthreads();
  }

  // epilogue: C/D mapping col=lane&15, row=(lane>>4)*4+reg [m89/m91 verified]
#pragma unroll
  for (int mm = 0; mm < 4; ++mm) {
    int trow = wr * 64 + mm * 16 + lk * 4;
#pragma unroll
    for (int reg = 0; reg < 4; ++reg) {
      int grow = bm * 128 + trow + reg;
      size_t obase;
      if (which == 0) {            // A_full row -> token 5p+4
        int b = grow >> 7, p = grow & 127;
        obase = (size_t)(b * 640 + 5 * p + 4) * 768;
      } else {                     // A_sub row -> token 5p+s
        int b = grow >> 9, tt = grow & 511, p = tt >> 2, s = tt & 3;
        obase = (size_t)(b * 640 + 5 * p + s) * 768;
      }
#pragma unroll
      for (int nn = 0; nn < 4; ++nn) {
        int gcol = bn * 128 + wc * 64 + nn * 16 + lr;
        out[obase + gcol] = acc[mm][nn][reg] + bias[gcol];
      }
    }
  }
}

extern "C" void kernel_launch(void* const* d_in, const int* in_sizes, int n_in,
                              void* d_out, int out_size, void* d_ws, size_t ws_size,
                              hipStream_t stream) {
  const float* x  = (const float*)d_in[0];
  // d_in[1] importance_w, d_in[4] num_patches: structure is static (see header)
  const float* pw = (const float*)d_in[2];
  const float* pb = (const float*)d_in[3];
  float* out = (float*)d_out;

  unsigned short* Af   = (unsigned short*)d_ws;       // 4096*3072  = 12,582,912
  unsigned short* Asub = Af + 12582912;               // 16384*768  = 12,582,912
  unsigned short* Wf   = Asub + 12582912;             // 768*3072   =  2,359,296
  unsigned short* Ws   = Wf + 2359296;                // 768*768    =    589,824
  // total ws: 56,229,888 bytes

  prep_wfull<<<2304, 256, 0, stream>>>(pw, Wf);
  prep_wsub<<<576, 256, 0, stream>>>(pw, Ws);
  gather_full<<<12288, 256, 0, stream>>>(x, Af);
  gather_sub<<<12288, 256, 0, stream>>>(x, Asub);
  gemm_kernel<<<960, 256, 0, stream>>>(Af, Asub, Wf, Ws, pb, out);
}

// Round 3
// 255.193 us; speedup vs baseline: 1.0134x; 1.0134x over previous
//
#include <hip/hip_runtime.h>
#include <stdint.h>

// ---------------------------------------------------------------------------
// IEViT adaptive patch embedding, MI355X/gfx950.  Round 3: balanced split-K.
//   even patch i=2p  -> 4 sub tokens (16x16, averaged kernel)
//   odd  patch i=2p+1-> 1 full token (32x32, full kernel)
//   tokens per pair p: [sub(0,0),sub(0,1),sub(1,0),sub(1,1),full] at 5p..5p+4
// GEMM-full: M=4096 K=3072 N=768 -> split-K=4 (partials bf16 in ws + reduce)
// GEMM-sub:  M=16384 K=768 N=768 -> direct write
// All 1536 gemm blocks do identical work: 128x128 tile, 12 K-steps of 64.
// ---------------------------------------------------------------------------

typedef __attribute__((ext_vector_type(8))) short bf16x8;
typedef __attribute__((ext_vector_type(4))) float f32x4;

__device__ __forceinline__ unsigned short f2bf(float f) {
  union { float f; unsigned u; } v; v.f = f;
  return (unsigned short)((v.u + 0x7fffu + ((v.u >> 16) & 1u)) >> 16);  // RNE
}
__device__ __forceinline__ float bf2f(unsigned short h) {
  union { unsigned u; float f; } v; v.u = ((unsigned)h) << 16; return v.f;
}

// ---- fused prep+gather: one kernel, 4 block ranges -------------------------
// [0,2304): Wf cast | [2304,2880): Ws avg | [2880,15168): Af | [15168,27456): Asub
__global__ __launch_bounds__(256) void prep_gather(
    const float* __restrict__ x, const float* __restrict__ pw,
    unsigned short* __restrict__ Wf, unsigned short* __restrict__ Ws,
    unsigned short* __restrict__ Af, unsigned short* __restrict__ Asub) {
  int bid = blockIdx.x, t = threadIdx.x;
  if (bid < 2304) {                      // cast patch_weight -> bf16 (B^T layout)
    int g = bid * 256 + t;               // 589,824 float4 groups
    float4 v = ((const float4*)pw)[g];
    ((ushort4*)Wf)[g] = make_ushort4(f2bf(v.x), f2bf(v.y), f2bf(v.z), f2bf(v.w));
  } else if (bid < 2880) {               // w_sub: reshape(E,C,2,2,16,16).mean(2,3)
    int g = (bid - 2304) * 256 + t;      // 147,456: w_sub[e,c,s,t] averages rows
    int e = g / 192;                     // {s>>1, 8+, 16+, 24+} of col 16*(s&1)+t
    int rem = g - e * 192;
    int cc = rem >> 6, r2 = rem & 63, s = r2 >> 2, t4 = r2 & 3;
    const float* base = pw + ((size_t)((e * 3 + cc) * 32 + (s >> 1)) * 32
                              + 16 * (s & 1) + 4 * t4);
    float4 q0 = *(const float4*)(base);
    float4 q1 = *(const float4*)(base + 8 * 32);
    float4 q2 = *(const float4*)(base + 16 * 32);
    float4 q3 = *(const float4*)(base + 24 * 32);
    ((ushort4*)Ws)[g] = make_ushort4(
        f2bf(0.25f * (q0.x + q1.x + q2.x + q3.x)),
        f2bf(0.25f * (q0.y + q1.y + q2.y + q3.y)),
        f2bf(0.25f * (q0.z + q1.z + q2.z + q3.z)),
        f2bf(0.25f * (q0.w + q1.w + q2.w + q3.w)));
  } else if (bid < 15168) {              // odd patches -> Af (4096 x 3072)
    int g = (bid - 2880) * 256 + t;      // 3,145,728
    int m = g / 768, q = g - m * 768;
    int b = m >> 7, p = m & 127;
    int i = 2 * p + 1;
    int r = i >> 4, cpat = i & 15;
    int cc = q >> 8, rem = q & 255, ii = rem >> 3, jj4 = rem & 7;
    const float4* src = (const float4*)(x + ((size_t)((b * 3 + cc) * 512 + (r * 32 + ii)) * 512
                                             + cpat * 32 + jj4 * 4));
    float4 v = *src;
    ((ushort4*)Af)[g] = make_ushort4(f2bf(v.x), f2bf(v.y), f2bf(v.z), f2bf(v.w));
  } else {                               // even-patch sub-tiles -> Asub (16384 x 768)
    int g = (bid - 15168) * 256 + t;     // 3,145,728
    int m = g / 192, q = g - m * 192;
    int b = m >> 9, tt = m & 511;
    int p = tt >> 2, s = tt & 3, dr = s >> 1, dc = s & 1;
    int i = 2 * p;
    int r = i >> 4, cpat = i & 15;
    int cc = q >> 6, rem = q & 63, ii = rem >> 2, jj4 = rem & 3;
    int srow = r * 32 + dr * 16 + ii;
    int scol = cpat * 32 + dc * 16 + jj4 * 4;
    const float4* src = (const float4*)(x + ((size_t)((b * 3 + cc) * 512 + srow) * 512 + scol));
    float4 v = *src;
    ((ushort4*)Asub)[g] = make_ushort4(f2bf(v.x), f2bf(v.y), f2bf(v.z), f2bf(v.w));
  }
}

// ---- uniform 128x128-tile bf16 MFMA GEMM, 1536 blocks, 12 K-steps each -----
__global__ __launch_bounds__(256) void gemm_kernel(
    const unsigned short* __restrict__ Af, const unsigned short* __restrict__ Asub,
    const unsigned short* __restrict__ Wf, const unsigned short* __restrict__ Ws,
    const float* __restrict__ bias, unsigned short* __restrict__ Pf,
    float* __restrict__ out) {
  __shared__ unsigned short Asm[128 * 64];
  __shared__ unsigned short Bsm[128 * 64];

  // XCD swizzle: nwg=1536 = 8*192, bijective
  int bid = (blockIdx.x & 7) * 192 + (blockIdx.x >> 3);

  const unsigned short* Abase;
  const unsigned short* Bbase;
  int rsA, bm, bn, kofs, which, kc = 0;
  if (bid < 768) {                 // full GEMM partial: (bm,kc) groups of 6 bn
    which = 0;
    int grp = bid / 6; bn = bid - grp * 6;
    bm = grp >> 2; kc = grp & 3;
    rsA = 3072; kofs = kc * 768;
    Abase = Af + (size_t)bm * 128 * 3072;
    Bbase = Wf;
  } else {                         // sub GEMM: direct
    which = 1;
    int id = bid - 768;
    bm = id / 6; bn = id - bm * 6;
    rsA = 768; kofs = 0;
    Abase = Asub + (size_t)bm * 128 * 768;
    Bbase = Ws;
  }
  const unsigned short* Brow = Bbase + (size_t)bn * 128 * rsA;  // B row stride == rsA

  int t = threadIdx.x;
  int lane = t & 63;
  int wv = t >> 6, wr = wv >> 1, wc = wv & 1;   // 2x2 waves, 64x64 each
  int lr = lane & 15, lk = lane >> 4;

  f32x4 acc[4][4];
#pragma unroll
  for (int mm = 0; mm < 4; ++mm)
#pragma unroll
    for (int nn = 0; nn < 4; ++nn) acc[mm][nn] = (f32x4){0.f, 0.f, 0.f, 0.f};

  // staging: thread t -> row t/8, 16B chunk (t&7); 4 issues cover 128 rows
  const unsigned short* a_src = Abase + (size_t)(t >> 3) * rsA + (t & 7) * 8 + kofs;
  const unsigned short* b_src = Brow + (size_t)(t >> 3) * rsA + (t & 7) * 8 + kofs;
  unsigned short* as_dst = &Asm[t * 8];
  unsigned short* bs_dst = &Bsm[t * 8];

  for (int k0 = 0; k0 < 768; k0 += 64) {
#pragma unroll
    for (int is = 0; is < 4; ++is) {
      __builtin_amdgcn_global_load_lds(
          (const __attribute__((address_space(1))) void*)(a_src + (size_t)is * 32 * rsA + k0),
          (__attribute__((address_space(3))) void*)(as_dst + is * 2048), 16, 0, 0);
      __builtin_amdgcn_global_load_lds(
          (const __attribute__((address_space(1))) void*)(b_src + (size_t)is * 32 * rsA + k0),
          (__attribute__((address_space(3))) void*)(bs_dst + is * 2048), 16, 0, 0);
    }
    __syncthreads();
#pragma unroll
    for (int kk = 0; kk < 64; kk += 32) {
      bf16x8 af[4], bf[4];
#pragma unroll
      for (int mm = 0; mm < 4; ++mm)
        af[mm] = *(const bf16x8*)&Asm[(wr * 64 + mm * 16 + lr) * 64 + kk + lk * 8];
#pragma unroll
      for (int nn = 0; nn < 4; ++nn)
        bf[nn] = *(const bf16x8*)&Bsm[(wc * 64 + nn * 16 + lr) * 64 + kk + lk * 8];
#pragma unroll
      for (int mm = 0; mm < 4; ++mm)
#pragma unroll
        for (int nn = 0; nn < 4; ++nn)
          acc[mm][nn] = __builtin_amdgcn_mfma_f32_16x16x32_bf16(af[mm], bf[nn], acc[mm][nn], 0, 0, 0);
    }
    __syncthreads();
  }

  // epilogue: C/D mapping col=lane&15, row=(lane>>4)*4+reg [m89/m91 verified]
#pragma unroll
  for (int mm = 0; mm < 4; ++mm) {
    int trow = wr * 64 + mm * 16 + lk * 4;
#pragma unroll
    for (int reg = 0; reg < 4; ++reg) {
      int grow = bm * 128 + trow + reg;
      if (which == 0) {            // bf16 partial (no bias) -> Pf[kc][grow][col]
        unsigned short* pdst = Pf + ((size_t)(kc * 4096 + grow)) * 768;
#pragma unroll
        for (int nn = 0; nn < 4; ++nn) {
          int gcol = bn * 128 + wc * 64 + nn * 16 + lr;
          pdst[gcol] = f2bf(acc[mm][nn][reg]);
        }
      } else {                     // A_sub row -> token 5p+s, direct + bias
        int b = grow >> 9, tt2 = grow & 511, p = tt2 >> 2, s = tt2 & 3;
        size_t obase = (size_t)(b * 640 + 5 * p + s) * 768;
#pragma unroll
        for (int nn = 0; nn < 4; ++nn) {
          int gcol = bn * 128 + wc * 64 + nn * 16 + lr;
          out[obase + gcol] = acc[mm][nn][reg] + bias[gcol];
        }
      }
    }
  }
}

// ---- reduce split-K partials + bias, scatter to full-token rows ------------
__global__ __launch_bounds__(256) void reduce_full(
    const unsigned short* __restrict__ Pf, const float* __restrict__ bias,
    float* __restrict__ out) {
  int q = blockIdx.x * 256 + threadIdx.x;   // 786,432 float4 outputs
  int m = q / 192, c4 = q - m * 192;
  float4 sacc = ((const float4*)bias)[c4];
#pragma unroll
  for (int kc = 0; kc < 4; ++kc) {
    ushort4 u = ((const ushort4*)(Pf + ((size_t)(kc * 4096 + m)) * 768))[c4];
    sacc.x += bf2f(u.x); sacc.y += bf2f(u.y);
    sacc.z += bf2f(u.z); sacc.w += bf2f(u.w);
  }
  int b = m >> 7, p = m & 127;
  size_t obase = (size_t)(b * 640 + 5 * p + 4) * 768;
  ((float4*)(out + obase))[c4] = sacc;
}

extern "C" void kernel_launch(void* const* d_in, const int* in_sizes, int n_in,
                              void* d_out, int out_size, void* d_ws, size_t ws_size,
                              hipStream_t stream) {
  const float* x  = (const float*)d_in[0];
  // d_in[1] importance_w, d_in[4] num_patches: structure is static (see header)
  const float* pw = (const float*)d_in[2];
  const float* pb = (const float*)d_in[3];
  float* out = (float*)d_out;

  unsigned short* Af   = (unsigned short*)d_ws;       // 4096*3072  = 12,582,912 elems
  unsigned short* Asub = Af + 12582912;               // 16384*768  = 12,582,912
  unsigned short* Wf   = Asub + 12582912;             // 768*3072   =  2,359,296
  unsigned short* Ws   = Wf + 2359296;                // 768*768    =    589,824
  unsigned short* Pf   = Ws + 589824;                 // 4*4096*768 = 12,582,912
  // total ws: 81,395,712 bytes

  prep_gather<<<27456, 256, 0, stream>>>(x, pw, Wf, Ws, Af, Asub);
  gemm_kernel<<<1536, 256, 0, stream>>>(Af, Asub, Wf, Ws, pb, Pf, out);
  reduce_full<<<3072, 256, 0, stream>>>(Pf, pb, out);
}

// Round 4
// 244.625 us; speedup vs baseline: 1.0572x; 1.0432x over previous
//
#include <hip/hip_runtime.h>
#include <stdint.h>

// ---------------------------------------------------------------------------
// IEViT adaptive patch embedding, MI355X/gfx950.  Round 4: gather fused into
// GEMM A-staging (reg-staged f32->bf16 from x), no A materialization.
//   even patch i=2p  -> 4 sub tokens (16x16, averaged kernel)
//   odd  patch i=2p+1-> 1 full token (32x32, full kernel)
//   tokens per pair p: [sub(0,0),sub(0,1),sub(1,0),sub(1,1),full] at 5p..5p+4
// GEMM-full: M=4096 K=3072 N=768 -> split-K=4 (bf16 partials + reduce)
// GEMM-sub:  M=16384 K=768 N=768 -> direct write
// 1536 uniform blocks: 128x128 tile, 12 K-steps of BK=64.
//
// A-address algebra (verified): x[(b*3+cc)*512 + row][col] flattens to
//   b*786432 + cc*262144 + ii*512 + (row/col base)
// full: k=cc*1024+ii*32+jj (jj<32), row=r*32+ii, col=cp*32+jj
// sub:  k=cc*256 +ii*16+jj (jj<16), row=r*32+dr*16+ii, col=cp*32+dc*16+jj
// Per-thread 8-k chunk (k = kofs + (t&7)*8 + k0) is 8 contiguous floats in x
// for both cases (8 | 16 | 32 divisibility), float4-aligned.
// ---------------------------------------------------------------------------

typedef __attribute__((ext_vector_type(8))) short bf16x8;
typedef __attribute__((ext_vector_type(8))) unsigned short ushort8;
typedef __attribute__((ext_vector_type(4))) float f32x4;

__device__ __forceinline__ unsigned short f2bf(float f) {
  union { float f; unsigned u; } v; v.f = f;
  return (unsigned short)((v.u + 0x7fffu + ((v.u >> 16) & 1u)) >> 16);  // RNE
}
__device__ __forceinline__ float bf2f(unsigned short h) {
  union { unsigned u; float f; } v; v.u = ((unsigned)h) << 16; return v.f;
}

// ---- weight prep: [0,2304) cast Wf; [2304,2880) build Ws -------------------
__global__ __launch_bounds__(256) void prep_w(const float* __restrict__ pw,
                                              unsigned short* __restrict__ Wf,
                                              unsigned short* __restrict__ Ws) {
  int bid = blockIdx.x, t = threadIdx.x;
  if (bid < 2304) {                      // cast patch_weight -> bf16 (B^T layout)
    int g = bid * 256 + t;               // 589,824 float4 groups
    float4 v = ((const float4*)pw)[g];
    ((ushort4*)Wf)[g] = make_ushort4(f2bf(v.x), f2bf(v.y), f2bf(v.z), f2bf(v.w));
  } else {                               // w_sub: reshape(E,C,2,2,16,16).mean(2,3)
    int g = (bid - 2304) * 256 + t;      // w_sub[e,c,s,t] averages rows
    int e = g / 192;                     // {s>>1, 8+, 16+, 24+} of col 16*(s&1)+t
    int rem = g - e * 192;
    int cc = rem >> 6, r2 = rem & 63, s = r2 >> 2, t4 = r2 & 3;
    const float* base = pw + ((size_t)((e * 3 + cc) * 32 + (s >> 1)) * 32
                              + 16 * (s & 1) + 4 * t4);
    float4 q0 = *(const float4*)(base);
    float4 q1 = *(const float4*)(base + 8 * 32);
    float4 q2 = *(const float4*)(base + 16 * 32);
    float4 q3 = *(const float4*)(base + 24 * 32);
    ((ushort4*)Ws)[g] = make_ushort4(
        f2bf(0.25f * (q0.x + q1.x + q2.x + q3.x)),
        f2bf(0.25f * (q0.y + q1.y + q2.y + q3.y)),
        f2bf(0.25f * (q0.z + q1.z + q2.z + q3.z)),
        f2bf(0.25f * (q0.w + q1.w + q2.w + q3.w)));
  }
}

// ---- fused GEMM: A reg-staged from x (f32->bf16), B via global_load_lds ----
__global__ __launch_bounds__(256) void gemm_fused(
    const float* __restrict__ x,
    const unsigned short* __restrict__ Wf, const unsigned short* __restrict__ Ws,
    const float* __restrict__ bias, unsigned short* __restrict__ Pf,
    float* __restrict__ out) {
  __shared__ unsigned short Asm[128 * 64];
  __shared__ unsigned short Bsm[128 * 64];

  // XCD swizzle: nwg=1536 = 8*192 (bijective); groups the 6 bn of one (bm,kc)
  // on one XCD -> x re-reads are L2-local.
  int bid = (blockIdx.x & 7) * 192 + (blockIdx.x >> 3);

  const unsigned short* Bbase;
  int rsB, bm, bn, kofs, which, kc = 0;
  int ccsh, iish, iimask, jjmask;
  if (bid < 768) {                 // full GEMM partial: grp=(bm,kc), 6 bn each
    which = 0;
    int grp = bid / 6; bn = bid - grp * 6;
    bm = grp >> 2; kc = grp & 3;
    rsB = 3072; kofs = kc * 768;
    Bbase = Wf;
    ccsh = 10; iish = 5; iimask = 31; jjmask = 31;
  } else {                         // sub GEMM: direct
    which = 1;
    int id = bid - 768;
    bm = id / 6; bn = id - bm * 6;
    rsB = 768; kofs = 0;
    Bbase = Ws;
    ccsh = 8; iish = 4; iimask = 15; jjmask = 15;
  }

  int t = threadIdx.x;
  int lane = t & 63;
  int wv = t >> 6, wr = wv >> 1, wc = wv & 1;   // 2x2 waves, 64x64 each
  int lr = lane & 15, lk = lane >> 4;

  // A-staging: thread t -> tile rows (t>>3)+32*is, k-chunk (t&7)*8 (8 floats)
  int kbase = kofs + (t & 7) * 8;
  int abase[4];
#pragma unroll
  for (int is = 0; is < 4; ++is) {
    int m = bm * 128 + (t >> 3) + is * 32;
    int b, r, cp, extra;
    if (which == 0) {
      b = m >> 7; int p = m & 127; int i = 2 * p + 1;
      r = i >> 4; cp = i & 15; extra = 0;
    } else {
      b = m >> 9; int q = m & 511; int p = q >> 2, s = q & 3;
      int dr = s >> 1, dc = s & 1; int i = 2 * p;
      r = i >> 4; cp = i & 15; extra = dr * 8192 + dc * 16;
    }
    abase[is] = b * 786432 + r * 16384 + cp * 32 + extra;
  }
  const unsigned short* b_src = Bbase + (size_t)(bn * 128 + (t >> 3)) * rsB
                                + (t & 7) * 8 + kofs;
  unsigned short* as_dst = &Asm[t * 8];
  unsigned short* bs_dst = &Bsm[t * 8];

  f32x4 acc[4][4];
#pragma unroll
  for (int mm = 0; mm < 4; ++mm)
#pragma unroll
    for (int nn = 0; nn < 4; ++nn) acc[mm][nn] = (f32x4){0.f, 0.f, 0.f, 0.f};

  for (int k0 = 0; k0 < 768; k0 += 64) {
    // B: async direct-to-LDS (bf16 already)
#pragma unroll
    for (int is = 0; is < 4; ++is)
      __builtin_amdgcn_global_load_lds(
          (const __attribute__((address_space(1))) void*)(b_src + (size_t)is * 32 * rsB + k0),
          (__attribute__((address_space(3))) void*)(bs_dst + is * 2048), 16, 0, 0);
    // A: reg-stage 8 floats per row-slice, convert, one ds_write_b128 each
    float4 va[4][2];
    int k = kbase + k0;
    int koff = (k >> ccsh) * 262144 + ((k >> iish) & iimask) * 512 + (k & jjmask);
#pragma unroll
    for (int is = 0; is < 4; ++is) {
      const float4* s4 = (const float4*)(x + abase[is] + koff);
      va[is][0] = s4[0]; va[is][1] = s4[1];
    }
#pragma unroll
    for (int is = 0; is < 4; ++is) {
      ushort8 v;
      v[0] = f2bf(va[is][0].x); v[1] = f2bf(va[is][0].y);
      v[2] = f2bf(va[is][0].z); v[3] = f2bf(va[is][0].w);
      v[4] = f2bf(va[is][1].x); v[5] = f2bf(va[is][1].y);
      v[6] = f2bf(va[is][1].z); v[7] = f2bf(va[is][1].w);
      *(ushort8*)(as_dst + is * 2048) = v;
    }
    __syncthreads();
#pragma unroll
    for (int kk = 0; kk < 64; kk += 32) {
      bf16x8 af[4], bf[4];
#pragma unroll
      for (int mm = 0; mm < 4; ++mm)
        af[mm] = *(const bf16x8*)&Asm[(wr * 64 + mm * 16 + lr) * 64 + kk + lk * 8];
#pragma unroll
      for (int nn = 0; nn < 4; ++nn)
        bf[nn] = *(const bf16x8*)&Bsm[(wc * 64 + nn * 16 + lr) * 64 + kk + lk * 8];
#pragma unroll
      for (int mm = 0; mm < 4; ++mm)
#pragma unroll
        for (int nn = 0; nn < 4; ++nn)
          acc[mm][nn] = __builtin_amdgcn_mfma_f32_16x16x32_bf16(af[mm], bf[nn], acc[mm][nn], 0, 0, 0);
    }
    __syncthreads();
  }

  // epilogue: C/D mapping col=lane&15, row=(lane>>4)*4+reg [m89/m91 verified]
#pragma unroll
  for (int mm = 0; mm < 4; ++mm) {
    int trow = wr * 64 + mm * 16 + lk * 4;
#pragma unroll
    for (int reg = 0; reg < 4; ++reg) {
      int grow = bm * 128 + trow + reg;
      if (which == 0) {            // bf16 partial (no bias) -> Pf[kc][grow][col]
        unsigned short* pdst = Pf + ((size_t)(kc * 4096 + grow)) * 768;
#pragma unroll
        for (int nn = 0; nn < 4; ++nn) {
          int gcol = bn * 128 + wc * 64 + nn * 16 + lr;
          pdst[gcol] = f2bf(acc[mm][nn][reg]);
        }
      } else {                     // A_sub row -> token 5p+s, direct + bias
        int b = grow >> 9, tt2 = grow & 511, p = tt2 >> 2, s = tt2 & 3;
        size_t obase = (size_t)(b * 640 + 5 * p + s) * 768;
#pragma unroll
        for (int nn = 0; nn < 4; ++nn) {
          int gcol = bn * 128 + wc * 64 + nn * 16 + lr;
          out[obase + gcol] = acc[mm][nn][reg] + bias[gcol];
        }
      }
    }
  }
}

// ---- reduce split-K partials + bias, scatter to full-token rows ------------
__global__ __launch_bounds__(256) void reduce_full(
    const unsigned short* __restrict__ Pf, const float* __restrict__ bias,
    float* __restrict__ out) {
  int q = blockIdx.x * 256 + threadIdx.x;   // 786,432 float4 outputs
  int m = q / 192, c4 = q - m * 192;
  float4 sacc = ((const float4*)bias)[c4];
#pragma unroll
  for (int kc = 0; kc < 4; ++kc) {
    ushort4 u = ((const ushort4*)(Pf + ((size_t)(kc * 4096 + m)) * 768))[c4];
    sacc.x += bf2f(u.x); sacc.y += bf2f(u.y);
    sacc.z += bf2f(u.z); sacc.w += bf2f(u.w);
  }
  int b = m >> 7, p = m & 127;
  size_t obase = (size_t)(b * 640 + 5 * p + 4) * 768;
  ((float4*)(out + obase))[c4] = sacc;
}

extern "C" void kernel_launch(void* const* d_in, const int* in_sizes, int n_in,
                              void* d_out, int out_size, void* d_ws, size_t ws_size,
                              hipStream_t stream) {
  const float* x  = (const float*)d_in[0];
  // d_in[1] importance_w, d_in[4] num_patches: structure is static (see header)
  const float* pw = (const float*)d_in[2];
  const float* pb = (const float*)d_in[3];
  float* out = (float*)d_out;

  unsigned short* Wf = (unsigned short*)d_ws;   // 768*3072   =  2,359,296 elems
  unsigned short* Ws = Wf + 2359296;            // 768*768    =    589,824
  unsigned short* Pf = Ws + 589824;             // 4*4096*768 = 12,582,912
  // total ws: 31,064,064 bytes

  prep_w<<<2880, 256, 0, stream>>>(pw, Wf, Ws);
  gemm_fused<<<1536, 256, 0, stream>>>(x, Wf, Ws, pb, Pf, out);
  reduce_full<<<3072, 256, 0, stream>>>(Pf, pb, out);
}